// Round 1
// baseline (1542.807 us; speedup 1.0000x reference)
//
#include <hip/hip_runtime.h>

// ---------------------------------------------------------------------------
// GCN: 4 layers of  h' = A_hat_norm (h @ W) + b   on fixed graph, fp32.
// A-normalization: deg[i] = in_degree(i) + 1 (self loop), dinv = 1/sqrt(deg),
// msg(src->dst) = (hW)[src] * dinv[src] * dinv[dst].
// Strategy: g = (h@W) * dinv[row]  (GEMM epilogue), then per-dst:
//   h'[dst] = dinv[dst] * ( g[dst] + sum_{src in N(dst)} g[src] ) + b
// (g[dst] term = self loop). CSR built per call from edge list.
// ---------------------------------------------------------------------------

#define FEAT 128
#define EMB 64

// ---------------- CSR build ----------------

__global__ void init_deg_k(int* __restrict__ deg, int N) {
    int i = blockIdx.x * blockDim.x + threadIdx.x;
    if (i < N) deg[i] = 1;  // self loop
}

__global__ void degree_k(const int* __restrict__ dst, int* __restrict__ deg, int E) {
    int idx = blockIdx.x * blockDim.x + threadIdx.x;
    int stride = gridDim.x * blockDim.x;
    for (int e = idx; e < E; e += stride) {
        atomicAdd(&deg[dst[e]], 1);
    }
}

__global__ void dinv_k(const int* __restrict__ deg, float* __restrict__ dinv, int N) {
    int i = blockIdx.x * blockDim.x + threadIdx.x;
    if (i < N) dinv[i] = 1.0f / sqrtf((float)deg[i]);
}

// inclusive scan of indegree (deg-1) within each 256-block; block sums out.
__global__ void scan1_k(const int* __restrict__ deg, int* __restrict__ inc,
                        int* __restrict__ bsum, int N) {
    __shared__ int s[256];
    int i = blockIdx.x * 256 + threadIdx.x;
    int v = (i < N) ? (deg[i] - 1) : 0;
    s[threadIdx.x] = v;
    __syncthreads();
    for (int off = 1; off < 256; off <<= 1) {
        int t = (threadIdx.x >= off) ? s[threadIdx.x - off] : 0;
        __syncthreads();
        s[threadIdx.x] += t;
        __syncthreads();
    }
    if (i < N) inc[i] = s[threadIdx.x];
    if (threadIdx.x == 255) bsum[blockIdx.x] = s[255];
}

// exclusive scan of block sums (nb <= 512), in place.
__global__ void scan2_k(int* __restrict__ bsum, int nb) {
    __shared__ int s[512];
    int v = (threadIdx.x < nb) ? bsum[threadIdx.x] : 0;
    s[threadIdx.x] = v;
    __syncthreads();
    for (int off = 1; off < 512; off <<= 1) {
        int t = (threadIdx.x >= off) ? s[threadIdx.x - off] : 0;
        __syncthreads();
        s[threadIdx.x] += t;
        __syncthreads();
    }
    if (threadIdx.x < nb) bsum[threadIdx.x] = s[threadIdx.x] - v;  // exclusive
}

__global__ void scan3_k(const int* __restrict__ inc, const int* __restrict__ bsum,
                        const int* __restrict__ deg, int* __restrict__ rowptr,
                        int* __restrict__ cursor, int N, int E) {
    int i = blockIdx.x * 256 + threadIdx.x;
    if (i < N) {
        int excl = inc[i] + bsum[blockIdx.x] - (deg[i] - 1);
        rowptr[i] = excl;
        cursor[i] = excl;
        if (i == N - 1) rowptr[N] = E;
    }
}

__global__ void fill_csr_k(const int* __restrict__ src, const int* __restrict__ dst,
                           int* __restrict__ cursor, int* __restrict__ col, int E) {
    int idx = blockIdx.x * blockDim.x + threadIdx.x;
    int stride = gridDim.x * blockDim.x;
    for (int e = idx; e < E; e += stride) {
        int d = dst[e];
        int p = atomicAdd(&cursor[d], 1);
        col[p] = src[e];
    }
}

// ---------------- GEMM + dinv row-scale:  G = (H @ W) * dinv[row] ----------------
// Block: 256 threads -> 64 rows x 64 cols, each thread 4x4 outputs.
template <int K>
__global__ __launch_bounds__(256) void gemm_scale_k(
    const float* __restrict__ H, const float* __restrict__ W,
    const float* __restrict__ dinv, float* __restrict__ G, int N) {
    __shared__ float Ws[K * EMB];
    int t = threadIdx.x;
    for (int i = t * 4; i < K * EMB; i += 1024) {
        *(float4*)(Ws + i) = *(const float4*)(W + i);
    }
    __syncthreads();

    int tc = t & 15;   // col group
    int tr = t >> 4;   // row group
    int j0 = tc * 4;
    int r0 = blockIdx.x * 64 + tr * 4;
    if (r0 >= N) return;

    int r[4];
#pragma unroll
    for (int i = 0; i < 4; i++) r[i] = (r0 + i < N) ? (r0 + i) : (N - 1);

    float acc[4][4] = {{0.f}};
    for (int k = 0; k < K; k += 4) {
        float4 a[4];
#pragma unroll
        for (int i = 0; i < 4; i++)
            a[i] = *(const float4*)(H + (size_t)r[i] * K + k);
#pragma unroll
        for (int kk = 0; kk < 4; kk++) {
            float4 wv = *(const float4*)(Ws + (k + kk) * EMB + j0);
#pragma unroll
            for (int i = 0; i < 4; i++) {
                float av = (kk == 0) ? a[i].x : (kk == 1) ? a[i].y : (kk == 2) ? a[i].z : a[i].w;
                acc[i][0] = fmaf(av, wv.x, acc[i][0]);
                acc[i][1] = fmaf(av, wv.y, acc[i][1]);
                acc[i][2] = fmaf(av, wv.z, acc[i][2]);
                acc[i][3] = fmaf(av, wv.w, acc[i][3]);
            }
        }
    }
#pragma unroll
    for (int i = 0; i < 4; i++) {
        if (r0 + i < N) {
            float s = dinv[r0 + i];
            float4 o = make_float4(acc[i][0] * s, acc[i][1] * s, acc[i][2] * s, acc[i][3] * s);
            *(float4*)(G + (size_t)(r0 + i) * EMB + j0) = o;
        }
    }
}

// ---------------- Aggregation: one wave per node, one lane per feature ----------------

__device__ __forceinline__ float agg_node(const float* __restrict__ G,
                                          const int* __restrict__ col,
                                          int s, int e, int node, int lane) {
    float a0 = G[(size_t)node * EMB + lane];  // self loop
    float a1 = 0.f, a2 = 0.f, a3 = 0.f;
    int i = s;
    for (; i + 4 <= e; i += 4) {
        int s0 = __builtin_amdgcn_readfirstlane(col[i]);
        int s1 = __builtin_amdgcn_readfirstlane(col[i + 1]);
        int s2 = __builtin_amdgcn_readfirstlane(col[i + 2]);
        int s3 = __builtin_amdgcn_readfirstlane(col[i + 3]);
        float g0 = G[(size_t)s0 * EMB + lane];
        float g1 = G[(size_t)s1 * EMB + lane];
        float g2 = G[(size_t)s2 * EMB + lane];
        float g3 = G[(size_t)s3 * EMB + lane];
        a0 += g0; a1 += g1; a2 += g2; a3 += g3;
    }
    for (; i < e; i++) {
        int s0 = __builtin_amdgcn_readfirstlane(col[i]);
        a0 += G[(size_t)s0 * EMB + lane];
    }
    return (a0 + a1) + (a2 + a3);
}

__global__ __launch_bounds__(256) void agg_k(
    const float* __restrict__ G, const float* __restrict__ dinv,
    const int* __restrict__ rowptr, const int* __restrict__ col,
    const float* __restrict__ bias, float* __restrict__ Hout, int N) {
    int gw = (blockIdx.x * 256 + threadIdx.x) >> 6;
    int lane = threadIdx.x & 63;
    if (gw >= N) return;
    int s = rowptr[gw], e = rowptr[gw + 1];
    float acc = agg_node(G, col, s, e, gw, lane);
    Hout[(size_t)gw * EMB + lane] = acc * dinv[gw] + bias[lane];
}

// Final layer: also project y @ Wout + bout into Out.
__global__ __launch_bounds__(256) void agg_final_k(
    const float* __restrict__ G, const float* __restrict__ dinv,
    const int* __restrict__ rowptr, const int* __restrict__ col,
    const float* __restrict__ bias, const float* __restrict__ Wout,
    const float* __restrict__ bout, float* __restrict__ Y,
    float* __restrict__ Out, int N) {
    int gw = (blockIdx.x * 256 + threadIdx.x) >> 6;
    int lane = threadIdx.x & 63;
    if (gw >= N) return;
    int s = rowptr[gw], e = rowptr[gw + 1];
    float acc = agg_node(G, col, s, e, gw, lane);
    float val = acc * dinv[gw] + bias[lane];
    Y[(size_t)gw * EMB + lane] = val;
    float p = val * Wout[lane];
#pragma unroll
    for (int off = 32; off > 0; off >>= 1) p += __shfl_down(p, off, 64);
    if (lane == 0) Out[gw] = p + bout[0];
}

// ---------------- launch ----------------

extern "C" void kernel_launch(void* const* d_in, const int* in_sizes, int n_in,
                              void* d_out, int out_size, void* d_ws, size_t ws_size,
                              hipStream_t stream) {
    const float* x    = (const float*)d_in[0];
    const int*   ei   = (const int*)d_in[1];
    const float* W0   = (const float*)d_in[3];
    const float* b0   = (const float*)d_in[4];
    const float* W1   = (const float*)d_in[5];
    const float* b1   = (const float*)d_in[6];
    const float* W2   = (const float*)d_in[7];
    const float* b2   = (const float*)d_in[8];
    const float* W3   = (const float*)d_in[9];
    const float* b3   = (const float*)d_in[10];
    const float* Wout = (const float*)d_in[11];
    const float* bout = (const float*)d_in[12];

    const int N = in_sizes[0] / FEAT;      // 100000
    const int E = in_sizes[1] / 2;         // 3200000
    const int* srcp = ei;                  // edge_index[0]
    const int* dstp = ei + E;              // edge_index[1]

    // workspace layout (all regions padded to 64 elems for float4 alignment)
    const int NP = ((N + 64) + 63) / 64 * 64;   // holds N+1
    int* deg     = (int*)d_ws;
    float* dinv  = (float*)(deg + NP);
    int* rowptr  = (int*)(dinv + NP);
    int* cursor  = rowptr + NP;
    int* inc     = cursor + NP;
    int* bsum    = inc + NP;
    int* col     = bsum + 1024;
    float* bufA  = (float*)(col + ((E + 63) / 64) * 64);

    float* Out = (float*)d_out;
    float* Y   = Out + N;                 // reuse y-region of d_out as ping-pong buffer

    const int nb = (N + 255) / 256;       // 391 (<=512 for scan2)
    const int gemm_blocks = (N + 63) / 64;
    const int agg_blocks  = (N + 3) / 4;

    // --- CSR build ---
    init_deg_k<<<nb, 256, 0, stream>>>(deg, N);
    degree_k<<<4096, 256, 0, stream>>>(dstp, deg, E);
    dinv_k<<<nb, 256, 0, stream>>>(deg, dinv, N);
    scan1_k<<<nb, 256, 0, stream>>>(deg, inc, bsum, N);
    scan2_k<<<1, 512, 0, stream>>>(bsum, nb);
    scan3_k<<<nb, 256, 0, stream>>>(inc, bsum, deg, rowptr, cursor, N, E);
    fill_csr_k<<<4096, 256, 0, stream>>>(srcp, dstp, cursor, col, E);

    // --- layer 0 (K=128) ---
    gemm_scale_k<FEAT><<<gemm_blocks, 256, 0, stream>>>(x, W0, dinv, bufA, N);
    agg_k<<<agg_blocks, 256, 0, stream>>>(bufA, dinv, rowptr, col, b0, Y, N);
    // --- layer 1 ---
    gemm_scale_k<EMB><<<gemm_blocks, 256, 0, stream>>>(Y, W1, dinv, bufA, N);
    agg_k<<<agg_blocks, 256, 0, stream>>>(bufA, dinv, rowptr, col, b1, Y, N);
    // --- layer 2 ---
    gemm_scale_k<EMB><<<gemm_blocks, 256, 0, stream>>>(Y, W2, dinv, bufA, N);
    agg_k<<<agg_blocks, 256, 0, stream>>>(bufA, dinv, rowptr, col, b2, Y, N);
    // --- layer 3 + output projection ---
    gemm_scale_k<EMB><<<gemm_blocks, 256, 0, stream>>>(Y, W3, dinv, bufA, N);
    agg_final_k<<<agg_blocks, 256, 0, stream>>>(bufA, dinv, rowptr, col, b3, Wout, bout,
                                                Y, Out, N);
}

// Round 2
// 1106.574 us; speedup vs baseline: 1.3942x; 1.3942x over previous
//
#include <hip/hip_runtime.h>

// ---------------------------------------------------------------------------
// GCN: 4 layers of  h' = A_hat_norm (h @ W) + b   on fixed graph, fp32.
// deg[i] = in_degree(i) + 1 (self loop), dinv = 1/sqrt(deg),
// msg(src->dst) = (hW)[src] * dinv[src] * dinv[dst].
// g = (h@W) * dinv[row]  (GEMM epilogue), then per-dst:
//   h'[dst] = dinv[dst] * ( g[dst] + sum_{src in N(dst)} g[src] ) + b
// CSR built per call from edge list.
// R2: gemm_scale_k rewritten — R1 version fully unrolled the k-loop,
// hoisted ~128 float4 loads, spilled (VGPR=256, 492 MB scratch writes,
// 465 us/dispatch). Now: manual 1-deep load pipeline, #pragma unroll 1,
// __launch_bounds__(256,4) caps VGPR at 128.
// ---------------------------------------------------------------------------

#define FEAT 128
#define EMB 64

// ---------------- CSR build ----------------

__global__ void init_deg_k(int* __restrict__ deg, int N) {
    int i = blockIdx.x * blockDim.x + threadIdx.x;
    if (i < N) deg[i] = 1;  // self loop
}

__global__ void degree_k(const int* __restrict__ dst, int* __restrict__ deg, int E) {
    int idx = blockIdx.x * blockDim.x + threadIdx.x;
    int stride = gridDim.x * blockDim.x;
    for (int e = idx; e < E; e += stride) {
        atomicAdd(&deg[dst[e]], 1);
    }
}

__global__ void dinv_k(const int* __restrict__ deg, float* __restrict__ dinv, int N) {
    int i = blockIdx.x * blockDim.x + threadIdx.x;
    if (i < N) dinv[i] = 1.0f / sqrtf((float)deg[i]);
}

// inclusive scan of indegree (deg-1) within each 256-block; block sums out.
__global__ void scan1_k(const int* __restrict__ deg, int* __restrict__ inc,
                        int* __restrict__ bsum, int N) {
    __shared__ int s[256];
    int i = blockIdx.x * 256 + threadIdx.x;
    int v = (i < N) ? (deg[i] - 1) : 0;
    s[threadIdx.x] = v;
    __syncthreads();
    for (int off = 1; off < 256; off <<= 1) {
        int t = (threadIdx.x >= off) ? s[threadIdx.x - off] : 0;
        __syncthreads();
        s[threadIdx.x] += t;
        __syncthreads();
    }
    if (i < N) inc[i] = s[threadIdx.x];
    if (threadIdx.x == 255) bsum[blockIdx.x] = s[255];
}

// exclusive scan of block sums (nb <= 512), in place.
__global__ void scan2_k(int* __restrict__ bsum, int nb) {
    __shared__ int s[512];
    int v = (threadIdx.x < nb) ? bsum[threadIdx.x] : 0;
    s[threadIdx.x] = v;
    __syncthreads();
    for (int off = 1; off < 512; off <<= 1) {
        int t = (threadIdx.x >= off) ? s[threadIdx.x - off] : 0;
        __syncthreads();
        s[threadIdx.x] += t;
        __syncthreads();
    }
    if (threadIdx.x < nb) bsum[threadIdx.x] = s[threadIdx.x] - v;  // exclusive
}

__global__ void scan3_k(const int* __restrict__ inc, const int* __restrict__ bsum,
                        const int* __restrict__ deg, int* __restrict__ rowptr,
                        int* __restrict__ cursor, int N, int E) {
    int i = blockIdx.x * 256 + threadIdx.x;
    if (i < N) {
        int excl = inc[i] + bsum[blockIdx.x] - (deg[i] - 1);
        rowptr[i] = excl;
        cursor[i] = excl;
        if (i == N - 1) rowptr[N] = E;
    }
}

__global__ void fill_csr_k(const int* __restrict__ src, const int* __restrict__ dst,
                           int* __restrict__ cursor, int* __restrict__ col, int E) {
    int idx = blockIdx.x * blockDim.x + threadIdx.x;
    int stride = gridDim.x * blockDim.x;
    for (int e = idx; e < E; e += stride) {
        int d = dst[e];
        int p = atomicAdd(&cursor[d], 1);
        col[p] = src[e];
    }
}

// ---------------- GEMM + dinv row-scale:  G = (H @ W) * dinv[row] ----------------
// Block: 256 threads -> 64 rows x 64 cols, each thread 4x4 outputs.
// Manual 1-deep pipeline on the A loads; unroll 1 keeps VGPR < 128.
template <int K>
__global__ __launch_bounds__(256, 4) void gemm_scale_k(
    const float* __restrict__ H, const float* __restrict__ W,
    const float* __restrict__ dinv, float* __restrict__ G, int N) {
    __shared__ float Ws[K * EMB];
    int t = threadIdx.x;
    for (int i = t * 4; i < K * EMB; i += 1024) {
        *(float4*)(Ws + i) = *(const float4*)(W + i);
    }
    __syncthreads();

    int tc = t & 15;   // col group -> 4 cols
    int tr = t >> 4;   // row group -> 4 rows
    int j0 = tc * 4;
    int r0 = blockIdx.x * 64 + tr * 4;
    if (r0 >= N) return;

    const float* hp[4];
#pragma unroll
    for (int i = 0; i < 4; i++) {
        int r = (r0 + i < N) ? (r0 + i) : (N - 1);
        hp[i] = H + (size_t)r * K;
    }

    float acc[4][4] = {{0.f}};
    float4 a[4], an[4];
#pragma unroll
    for (int i = 0; i < 4; i++) a[i] = *(const float4*)(hp[i]);

#pragma unroll 1
    for (int k = 0; k < K; k += 4) {
        if (k + 4 < K) {
#pragma unroll
            for (int i = 0; i < 4; i++) an[i] = *(const float4*)(hp[i] + k + 4);
        }
#pragma unroll
        for (int kk = 0; kk < 4; kk++) {
            float4 wv = *(const float4*)(Ws + (k + kk) * EMB + j0);
#pragma unroll
            for (int i = 0; i < 4; i++) {
                float av = (kk == 0) ? a[i].x : (kk == 1) ? a[i].y : (kk == 2) ? a[i].z : a[i].w;
                acc[i][0] = fmaf(av, wv.x, acc[i][0]);
                acc[i][1] = fmaf(av, wv.y, acc[i][1]);
                acc[i][2] = fmaf(av, wv.z, acc[i][2]);
                acc[i][3] = fmaf(av, wv.w, acc[i][3]);
            }
        }
#pragma unroll
        for (int i = 0; i < 4; i++) a[i] = an[i];
    }

#pragma unroll
    for (int i = 0; i < 4; i++) {
        if (r0 + i < N) {
            float s = dinv[r0 + i];
            float4 o = make_float4(acc[i][0] * s, acc[i][1] * s, acc[i][2] * s, acc[i][3] * s);
            *(float4*)(G + (size_t)(r0 + i) * EMB + j0) = o;
        }
    }
}

// ---------------- Aggregation: one wave per node, one lane per feature ----------------

__device__ __forceinline__ float agg_node(const float* __restrict__ G,
                                          const int* __restrict__ col,
                                          int s, int e, int node, int lane) {
    float a0 = G[(size_t)node * EMB + lane];  // self loop
    float a1 = 0.f, a2 = 0.f, a3 = 0.f;
    int i = s;
    for (; i + 4 <= e; i += 4) {
        int s0 = __builtin_amdgcn_readfirstlane(col[i]);
        int s1 = __builtin_amdgcn_readfirstlane(col[i + 1]);
        int s2 = __builtin_amdgcn_readfirstlane(col[i + 2]);
        int s3 = __builtin_amdgcn_readfirstlane(col[i + 3]);
        float g0 = G[(size_t)s0 * EMB + lane];
        float g1 = G[(size_t)s1 * EMB + lane];
        float g2 = G[(size_t)s2 * EMB + lane];
        float g3 = G[(size_t)s3 * EMB + lane];
        a0 += g0; a1 += g1; a2 += g2; a3 += g3;
    }
    for (; i < e; i++) {
        int s0 = __builtin_amdgcn_readfirstlane(col[i]);
        a0 += G[(size_t)s0 * EMB + lane];
    }
    return (a0 + a1) + (a2 + a3);
}

__global__ __launch_bounds__(256) void agg_k(
    const float* __restrict__ G, const float* __restrict__ dinv,
    const int* __restrict__ rowptr, const int* __restrict__ col,
    const float* __restrict__ bias, float* __restrict__ Hout, int N) {
    int gw = (blockIdx.x * 256 + threadIdx.x) >> 6;
    int lane = threadIdx.x & 63;
    if (gw >= N) return;
    int s = rowptr[gw], e = rowptr[gw + 1];
    float acc = agg_node(G, col, s, e, gw, lane);
    Hout[(size_t)gw * EMB + lane] = acc * dinv[gw] + bias[lane];
}

// Final layer: also project y @ Wout + bout into Out.
__global__ __launch_bounds__(256) void agg_final_k(
    const float* __restrict__ G, const float* __restrict__ dinv,
    const int* __restrict__ rowptr, const int* __restrict__ col,
    const float* __restrict__ bias, const float* __restrict__ Wout,
    const float* __restrict__ bout, float* __restrict__ Y,
    float* __restrict__ Out, int N) {
    int gw = (blockIdx.x * 256 + threadIdx.x) >> 6;
    int lane = threadIdx.x & 63;
    if (gw >= N) return;
    int s = rowptr[gw], e = rowptr[gw + 1];
    float acc = agg_node(G, col, s, e, gw, lane);
    float val = acc * dinv[gw] + bias[lane];
    Y[(size_t)gw * EMB + lane] = val;
    float p = val * Wout[lane];
#pragma unroll
    for (int off = 32; off > 0; off >>= 1) p += __shfl_down(p, off, 64);
    if (lane == 0) Out[gw] = p + bout[0];
}

// ---------------- launch ----------------

extern "C" void kernel_launch(void* const* d_in, const int* in_sizes, int n_in,
                              void* d_out, int out_size, void* d_ws, size_t ws_size,
                              hipStream_t stream) {
    const float* x    = (const float*)d_in[0];
    const int*   ei   = (const int*)d_in[1];
    const float* W0   = (const float*)d_in[3];
    const float* b0   = (const float*)d_in[4];
    const float* W1   = (const float*)d_in[5];
    const float* b1   = (const float*)d_in[6];
    const float* W2   = (const float*)d_in[7];
    const float* b2   = (const float*)d_in[8];
    const float* W3   = (const float*)d_in[9];
    const float* b3   = (const float*)d_in[10];
    const float* Wout = (const float*)d_in[11];
    const float* bout = (const float*)d_in[12];

    const int N = in_sizes[0] / FEAT;      // 100000
    const int E = in_sizes[1] / 2;         // 3200000
    const int* srcp = ei;                  // edge_index[0]
    const int* dstp = ei + E;              // edge_index[1]

    // workspace layout (all regions padded to 64 elems for float4 alignment)
    const int NP = ((N + 64) + 63) / 64 * 64;   // holds N+1
    int* deg     = (int*)d_ws;
    float* dinv  = (float*)(deg + NP);
    int* rowptr  = (int*)(dinv + NP);
    int* cursor  = rowptr + NP;
    int* inc     = cursor + NP;
    int* bsum    = inc + NP;
    int* col     = bsum + 1024;
    float* bufA  = (float*)(col + ((E + 63) / 64) * 64);

    float* Out = (float*)d_out;
    float* Y   = Out + N;                 // reuse y-region of d_out as ping-pong buffer

    const int nb = (N + 255) / 256;       // 391 (<=512 for scan2)
    const int gemm_blocks = (N + 63) / 64;
    const int agg_blocks  = (N + 3) / 4;

    // --- CSR build ---
    init_deg_k<<<nb, 256, 0, stream>>>(deg, N);
    degree_k<<<4096, 256, 0, stream>>>(dstp, deg, E);
    dinv_k<<<nb, 256, 0, stream>>>(deg, dinv, N);
    scan1_k<<<nb, 256, 0, stream>>>(deg, inc, bsum, N);
    scan2_k<<<1, 512, 0, stream>>>(bsum, nb);
    scan3_k<<<nb, 256, 0, stream>>>(inc, bsum, deg, rowptr, cursor, N, E);
    fill_csr_k<<<4096, 256, 0, stream>>>(srcp, dstp, cursor, col, E);

    // --- layer 0 (K=128) ---
    gemm_scale_k<FEAT><<<gemm_blocks, 256, 0, stream>>>(x, W0, dinv, bufA, N);
    agg_k<<<agg_blocks, 256, 0, stream>>>(bufA, dinv, rowptr, col, b0, Y, N);
    // --- layer 1 ---
    gemm_scale_k<EMB><<<gemm_blocks, 256, 0, stream>>>(Y, W1, dinv, bufA, N);
    agg_k<<<agg_blocks, 256, 0, stream>>>(bufA, dinv, rowptr, col, b1, Y, N);
    // --- layer 2 ---
    gemm_scale_k<EMB><<<gemm_blocks, 256, 0, stream>>>(Y, W2, dinv, bufA, N);
    agg_k<<<agg_blocks, 256, 0, stream>>>(bufA, dinv, rowptr, col, b2, Y, N);
    // --- layer 3 + output projection ---
    gemm_scale_k<EMB><<<gemm_blocks, 256, 0, stream>>>(Y, W3, dinv, bufA, N);
    agg_final_k<<<agg_blocks, 256, 0, stream>>>(bufA, dinv, rowptr, col, b3, Wout, bout,
                                                Y, Out, N);
}

// Round 3
// 916.826 us; speedup vs baseline: 1.6828x; 1.2070x over previous
//
#include <hip/hip_runtime.h>

// ---------------------------------------------------------------------------
// GCN: 4 layers of  h' = A_hat_norm (h @ W) + b   on fixed graph, fp32.
// deg[i] = in_degree(i) + 1 (self loop), dinv = 1/sqrt(deg),
// g = (h@W) * dinv[row]  (GEMM epilogue), then per-dst:
//   h'[dst] = dinv[dst] * ( g[dst] + sum_{src in N(dst)} g[src] ) + b
// R2: gemm spill fixed (unroll 1 + manual pipeline).
// R3: CSR fill rewritten. R2's fill_csr_k did 3.2M random 4B stores over a
// 12.8MB region from all XCDs -> 200MB HBM writes (64B/txn, no L2 merge),
// 272us. Now: two-level counting sort. bin_edges_k scatters into 391
// dst-range bins (runs per block are ~84B, single-CU writer -> L2 merges);
// fill_csr2_k does one block per bin with LDS cursors, scattering col
// within a ~32KB window (single-CU writer -> L2 merges).
// ---------------------------------------------------------------------------

#define FEAT 128
#define EMB 64
#define BINSHIFT 8
#define BINSIZE 256
#define NBIN 391          // ceil(100000/256); recomputed at runtime too
#define CHUNK 8192

// ---------------- CSR build ----------------

__global__ void init_deg_k(int* __restrict__ deg, int N) {
    int i = blockIdx.x * blockDim.x + threadIdx.x;
    if (i < N) deg[i] = 1;  // self loop
}

__global__ void degree_k(const int* __restrict__ dst, int* __restrict__ deg, int E) {
    int idx = blockIdx.x * blockDim.x + threadIdx.x;
    int stride = gridDim.x * blockDim.x;
    for (int e = idx; e < E; e += stride) {
        atomicAdd(&deg[dst[e]], 1);
    }
}

__global__ void dinv_k(const int* __restrict__ deg, float* __restrict__ dinv, int N) {
    int i = blockIdx.x * blockDim.x + threadIdx.x;
    if (i < N) dinv[i] = 1.0f / sqrtf((float)deg[i]);
}

// inclusive scan of indegree (deg-1) within each 256-block; block sums out.
__global__ void scan1_k(const int* __restrict__ deg, int* __restrict__ inc,
                        int* __restrict__ bsum, int N) {
    __shared__ int s[256];
    int i = blockIdx.x * 256 + threadIdx.x;
    int v = (i < N) ? (deg[i] - 1) : 0;
    s[threadIdx.x] = v;
    __syncthreads();
    for (int off = 1; off < 256; off <<= 1) {
        int t = (threadIdx.x >= off) ? s[threadIdx.x - off] : 0;
        __syncthreads();
        s[threadIdx.x] += t;
        __syncthreads();
    }
    if (i < N) inc[i] = s[threadIdx.x];
    if (threadIdx.x == 255) bsum[blockIdx.x] = s[255];
}

// exclusive scan of block sums (nb <= 512), in place.
__global__ void scan2_k(int* __restrict__ bsum, int nb) {
    __shared__ int s[512];
    int v = (threadIdx.x < nb) ? bsum[threadIdx.x] : 0;
    s[threadIdx.x] = v;
    __syncthreads();
    for (int off = 1; off < 512; off <<= 1) {
        int t = (threadIdx.x >= off) ? s[threadIdx.x - off] : 0;
        __syncthreads();
        s[threadIdx.x] += t;
        __syncthreads();
    }
    if (threadIdx.x < nb) bsum[threadIdx.x] = s[threadIdx.x] - v;  // exclusive
}

__global__ void scan3_k(const int* __restrict__ inc, const int* __restrict__ bsum,
                        const int* __restrict__ deg, int* __restrict__ rowptr,
                        int N, int E) {
    int i = blockIdx.x * 256 + threadIdx.x;
    if (i < N) {
        int excl = inc[i] + bsum[blockIdx.x] - (deg[i] - 1);
        rowptr[i] = excl;
        if (i == N - 1) rowptr[N] = E;
    }
}

__global__ void init_bincur_k(const int* __restrict__ rowptr, int* __restrict__ bincur,
                              int nbin) {
    int b = blockIdx.x * blockDim.x + threadIdx.x;
    if (b < nbin) bincur[b] = rowptr[b << BINSHIFT];
}

// Pass B: scatter edges into dst-range bins. One block per 8192-edge chunk.
// Output word: src | (dst&255)<<24  (src < 2^17 fits in 24 bits).
__global__ __launch_bounds__(256) void bin_edges_k(
    const int* __restrict__ src, const int* __restrict__ dst,
    int* __restrict__ bincur, int* __restrict__ ebuf, int E) {
    __shared__ int hist[NBIN];
    __shared__ int lcur[NBIN];
    int t = threadIdx.x;
    int base = blockIdx.x * CHUNK;
    int end = min(base + CHUNK, E);
    for (int i = t; i < NBIN; i += 256) hist[i] = 0;
    __syncthreads();
    for (int e = base + t; e < end; e += 256)
        atomicAdd(&hist[dst[e] >> BINSHIFT], 1);
    __syncthreads();
    for (int b = t; b < NBIN; b += 256) {
        int c = hist[b];
        lcur[b] = (c > 0) ? atomicAdd(&bincur[b], c) : 0;
    }
    __syncthreads();
    for (int e = base + t; e < end; e += 256) {
        int d = dst[e];
        int bin = d >> BINSHIFT;
        int r = atomicAdd(&lcur[bin], 1);
        ebuf[r] = src[e] | ((d & (BINSIZE - 1)) << 24);
    }
}

// Pass C: one block per bin; LDS per-node cursors; scatter col within bin window.
__global__ __launch_bounds__(256) void fill_csr2_k(
    const int* __restrict__ ebuf, const int* __restrict__ rowptr,
    int* __restrict__ col, int N) {
    __shared__ int lcur[BINSIZE];
    int b = blockIdx.x;
    int n0 = b << BINSHIFT;
    int nend = min(N, n0 + BINSIZE);
    int t = threadIdx.x;
    lcur[t] = (n0 + t < nend) ? rowptr[n0 + t] : 0;
    __syncthreads();
    int e0 = rowptr[n0];
    int e1 = rowptr[nend];
    for (int i = e0 + t; i < e1; i += 256) {
        int v = ebuf[i];
        int s = v & 0xFFFFFF;
        int dl = ((unsigned)v) >> 24;
        int p = atomicAdd(&lcur[dl], 1);
        col[p] = s;
    }
}

// ---------------- GEMM + dinv row-scale:  G = (H @ W) * dinv[row] ----------------
// Block: 256 threads -> 64 rows x 64 cols, each thread 4x4 outputs.
// Manual 1-deep pipeline on the A loads; unroll 1 keeps VGPR < 128.
template <int K>
__global__ __launch_bounds__(256, 4) void gemm_scale_k(
    const float* __restrict__ H, const float* __restrict__ W,
    const float* __restrict__ dinv, float* __restrict__ G, int N) {
    __shared__ float Ws[K * EMB];
    int t = threadIdx.x;
    for (int i = t * 4; i < K * EMB; i += 1024) {
        *(float4*)(Ws + i) = *(const float4*)(W + i);
    }
    __syncthreads();

    int tc = t & 15;   // col group -> 4 cols
    int tr = t >> 4;   // row group -> 4 rows
    int j0 = tc * 4;
    int r0 = blockIdx.x * 64 + tr * 4;
    if (r0 >= N) return;

    const float* hp[4];
#pragma unroll
    for (int i = 0; i < 4; i++) {
        int r = (r0 + i < N) ? (r0 + i) : (N - 1);
        hp[i] = H + (size_t)r * K;
    }

    float acc[4][4] = {{0.f}};
    float4 a[4], an[4];
#pragma unroll
    for (int i = 0; i < 4; i++) a[i] = *(const float4*)(hp[i]);

#pragma unroll 1
    for (int k = 0; k < K; k += 4) {
        if (k + 4 < K) {
#pragma unroll
            for (int i = 0; i < 4; i++) an[i] = *(const float4*)(hp[i] + k + 4);
        }
#pragma unroll
        for (int kk = 0; kk < 4; kk++) {
            float4 wv = *(const float4*)(Ws + (k + kk) * EMB + j0);
#pragma unroll
            for (int i = 0; i < 4; i++) {
                float av = (kk == 0) ? a[i].x : (kk == 1) ? a[i].y : (kk == 2) ? a[i].z : a[i].w;
                acc[i][0] = fmaf(av, wv.x, acc[i][0]);
                acc[i][1] = fmaf(av, wv.y, acc[i][1]);
                acc[i][2] = fmaf(av, wv.z, acc[i][2]);
                acc[i][3] = fmaf(av, wv.w, acc[i][3]);
            }
        }
#pragma unroll
        for (int i = 0; i < 4; i++) a[i] = an[i];
    }

#pragma unroll
    for (int i = 0; i < 4; i++) {
        if (r0 + i < N) {
            float s = dinv[r0 + i];
            float4 o = make_float4(acc[i][0] * s, acc[i][1] * s, acc[i][2] * s, acc[i][3] * s);
            *(float4*)(G + (size_t)(r0 + i) * EMB + j0) = o;
        }
    }
}

// ---------------- Aggregation: one wave per node, one lane per feature ----------------

__device__ __forceinline__ float agg_node(const float* __restrict__ G,
                                          const int* __restrict__ col,
                                          int s, int e, int node, int lane) {
    float a0 = G[(size_t)node * EMB + lane];  // self loop
    float a1 = 0.f, a2 = 0.f, a3 = 0.f;
    int i = s;
    for (; i + 4 <= e; i += 4) {
        int s0 = __builtin_amdgcn_readfirstlane(col[i]);
        int s1 = __builtin_amdgcn_readfirstlane(col[i + 1]);
        int s2 = __builtin_amdgcn_readfirstlane(col[i + 2]);
        int s3 = __builtin_amdgcn_readfirstlane(col[i + 3]);
        float g0 = G[(size_t)s0 * EMB + lane];
        float g1 = G[(size_t)s1 * EMB + lane];
        float g2 = G[(size_t)s2 * EMB + lane];
        float g3 = G[(size_t)s3 * EMB + lane];
        a0 += g0; a1 += g1; a2 += g2; a3 += g3;
    }
    for (; i < e; i++) {
        int s0 = __builtin_amdgcn_readfirstlane(col[i]);
        a0 += G[(size_t)s0 * EMB + lane];
    }
    return (a0 + a1) + (a2 + a3);
}

__global__ __launch_bounds__(256) void agg_k(
    const float* __restrict__ G, const float* __restrict__ dinv,
    const int* __restrict__ rowptr, const int* __restrict__ col,
    const float* __restrict__ bias, float* __restrict__ Hout, int N) {
    int gw = (blockIdx.x * 256 + threadIdx.x) >> 6;
    int lane = threadIdx.x & 63;
    if (gw >= N) return;
    int s = rowptr[gw], e = rowptr[gw + 1];
    float acc = agg_node(G, col, s, e, gw, lane);
    Hout[(size_t)gw * EMB + lane] = acc * dinv[gw] + bias[lane];
}

// Final layer: also project y @ Wout + bout into Out.
__global__ __launch_bounds__(256) void agg_final_k(
    const float* __restrict__ G, const float* __restrict__ dinv,
    const int* __restrict__ rowptr, const int* __restrict__ col,
    const float* __restrict__ bias, const float* __restrict__ Wout,
    const float* __restrict__ bout, float* __restrict__ Y,
    float* __restrict__ Out, int N) {
    int gw = (blockIdx.x * 256 + threadIdx.x) >> 6;
    int lane = threadIdx.x & 63;
    if (gw >= N) return;
    int s = rowptr[gw], e = rowptr[gw + 1];
    float acc = agg_node(G, col, s, e, gw, lane);
    float val = acc * dinv[gw] + bias[lane];
    Y[(size_t)gw * EMB + lane] = val;
    float p = val * Wout[lane];
#pragma unroll
    for (int off = 32; off > 0; off >>= 1) p += __shfl_down(p, off, 64);
    if (lane == 0) Out[gw] = p + bout[0];
}

// ---------------- launch ----------------

extern "C" void kernel_launch(void* const* d_in, const int* in_sizes, int n_in,
                              void* d_out, int out_size, void* d_ws, size_t ws_size,
                              hipStream_t stream) {
    const float* x    = (const float*)d_in[0];
    const int*   ei   = (const int*)d_in[1];
    const float* W0   = (const float*)d_in[3];
    const float* b0   = (const float*)d_in[4];
    const float* W1   = (const float*)d_in[5];
    const float* b1   = (const float*)d_in[6];
    const float* W2   = (const float*)d_in[7];
    const float* b2   = (const float*)d_in[8];
    const float* W3   = (const float*)d_in[9];
    const float* b3   = (const float*)d_in[10];
    const float* Wout = (const float*)d_in[11];
    const float* bout = (const float*)d_in[12];

    const int N = in_sizes[0] / FEAT;      // 100000
    const int E = in_sizes[1] / 2;         // 3200000
    const int* srcp = ei;                  // edge_index[0]
    const int* dstp = ei + E;              // edge_index[1]
    const int nbin = (N + BINSIZE - 1) / BINSIZE;   // 391

    // workspace layout (regions padded to 64 elems for float4 alignment)
    const int NP = ((N + 64) + 63) / 64 * 64;   // holds N+1
    int* deg     = (int*)d_ws;
    float* dinv  = (float*)(deg + NP);
    int* rowptr  = (int*)(dinv + NP);
    int* inc     = rowptr + NP;
    int* bsum    = inc + NP;
    int* bincur  = bsum + 1024;
    int* col     = bincur + 1024;
    float* bufA  = (float*)(col + ((E + 63) / 64) * 64);
    int* ebuf    = (int*)bufA;            // aliased: ebuf dead before first gemm

    float* Out = (float*)d_out;
    float* Y   = Out + N;                 // reuse y-region of d_out as ping-pong buffer

    const int nb = (N + 255) / 256;       // 391 (<=512 for scan2)
    const int gemm_blocks = (N + 63) / 64;
    const int agg_blocks  = (N + 3) / 4;
    const int nchunk = (E + CHUNK - 1) / CHUNK;

    // --- CSR build ---
    init_deg_k<<<nb, 256, 0, stream>>>(deg, N);
    degree_k<<<4096, 256, 0, stream>>>(dstp, deg, E);
    dinv_k<<<nb, 256, 0, stream>>>(deg, dinv, N);
    scan1_k<<<nb, 256, 0, stream>>>(deg, inc, bsum, N);
    scan2_k<<<1, 512, 0, stream>>>(bsum, nb);
    scan3_k<<<nb, 256, 0, stream>>>(inc, bsum, deg, rowptr, N, E);
    init_bincur_k<<<(nbin + 255) / 256, 256, 0, stream>>>(rowptr, bincur, nbin);
    bin_edges_k<<<nchunk, 256, 0, stream>>>(srcp, dstp, bincur, ebuf, E);
    fill_csr2_k<<<nbin, 256, 0, stream>>>(ebuf, rowptr, col, N);

    // --- layer 0 (K=128) ---
    gemm_scale_k<FEAT><<<gemm_blocks, 256, 0, stream>>>(x, W0, dinv, bufA, N);
    agg_k<<<agg_blocks, 256, 0, stream>>>(bufA, dinv, rowptr, col, b0, Y, N);
    // --- layer 1 ---
    gemm_scale_k<EMB><<<gemm_blocks, 256, 0, stream>>>(Y, W1, dinv, bufA, N);
    agg_k<<<agg_blocks, 256, 0, stream>>>(bufA, dinv, rowptr, col, b1, Y, N);
    // --- layer 2 ---
    gemm_scale_k<EMB><<<gemm_blocks, 256, 0, stream>>>(Y, W2, dinv, bufA, N);
    agg_k<<<agg_blocks, 256, 0, stream>>>(bufA, dinv, rowptr, col, b2, Y, N);
    // --- layer 3 + output projection ---
    gemm_scale_k<EMB><<<gemm_blocks, 256, 0, stream>>>(Y, W3, dinv, bufA, N);
    agg_final_k<<<agg_blocks, 256, 0, stream>>>(bufA, dinv, rowptr, col, b3, Wout, bout,
                                                Y, Out, N);
}

// Round 4
// 783.548 us; speedup vs baseline: 1.9690x; 1.1701x over previous
//
#include <hip/hip_runtime.h>

// ---------------------------------------------------------------------------
// GCN: 4 layers of  h' = A_hat_norm (h @ W) + b   on fixed graph, fp32.
// deg[i] = in_degree(i) + 1 (self loop), dinv = 1/sqrt(deg),
// g = (h@W) * dinv[row]  (GEMM epilogue), then per-dst:
//   h'[dst] = dinv[dst] * ( g[dst] + sum_{src in N(dst)} g[src] ) + b
// R2: gemm spill fixed (unroll 1 + manual pipeline).
// R3: CSR fill via 2-level counting sort (binned scatter, L2-merged).
// R4: degree_k removed. R3's degree_k did 3.2M device-scope atomics to a
// random 400KB array from all XCDs -> 100MB HBM RMW traffic, 128us. Now
// per-node degrees/scan/dinv/col-scatter all happen per-256-node-bin in
// LDS (build_csr_k); only per-bin totals (391 ints) use global atomics.
// ---------------------------------------------------------------------------

#define FEAT 128
#define EMB 64
#define BINSHIFT 8
#define BINSIZE 256
#define NBIN 391          // ceil(100000/256)
#define CHUNK 8192

// ---------------- CSR build ----------------

__global__ void zero_k(int* __restrict__ p, int n) {
    int i = blockIdx.x * blockDim.x + threadIdx.x;
    if (i < n) p[i] = 0;
}

// Pass A: per-bin edge counts. LDS histogram per chunk, one global atomic
// per (chunk, nonzero bin).
__global__ __launch_bounds__(256) void bin_count_k(
    const int* __restrict__ dst, int* __restrict__ bincnt, int E) {
    __shared__ int hist[NBIN];
    int t = threadIdx.x;
    int base = blockIdx.x * CHUNK;
    int end = min(base + CHUNK, E);
    for (int i = t; i < NBIN; i += 256) hist[i] = 0;
    __syncthreads();
    for (int e = base + t; e < end; e += 256)
        atomicAdd(&hist[dst[e] >> BINSHIFT], 1);
    __syncthreads();
    for (int b = t; b < NBIN; b += 256) {
        int c = hist[b];
        if (c > 0) atomicAdd(&bincnt[b], c);
    }
}

// exclusive scan of bin counts (NBIN <= 512), writes binptr + bincur.
__global__ void binscan_k(const int* __restrict__ bincnt, int* __restrict__ binptr,
                          int* __restrict__ bincur, int nbin, int E) {
    __shared__ int s[512];
    int t = threadIdx.x;
    int v = (t < nbin) ? bincnt[t] : 0;
    s[t] = v;
    __syncthreads();
    for (int off = 1; off < 512; off <<= 1) {
        int tv = (t >= off) ? s[t - off] : 0;
        __syncthreads();
        s[t] += tv;
        __syncthreads();
    }
    if (t < nbin) {
        int excl = s[t] - v;
        binptr[t] = excl;
        bincur[t] = excl;
    }
    if (t == 0) binptr[nbin] = E;
}

// Pass B: scatter edges into dst-range bins. One block per 8192-edge chunk.
// Output word: src | (dst&255)<<24  (src < 2^17 fits in 24 bits).
__global__ __launch_bounds__(256) void bin_edges_k(
    const int* __restrict__ src, const int* __restrict__ dst,
    int* __restrict__ bincur, int* __restrict__ ebuf, int E) {
    __shared__ int hist[NBIN];
    __shared__ int lcur[NBIN];
    int t = threadIdx.x;
    int base = blockIdx.x * CHUNK;
    int end = min(base + CHUNK, E);
    for (int i = t; i < NBIN; i += 256) hist[i] = 0;
    __syncthreads();
    for (int e = base + t; e < end; e += 256)
        atomicAdd(&hist[dst[e] >> BINSHIFT], 1);
    __syncthreads();
    for (int b = t; b < NBIN; b += 256) {
        int c = hist[b];
        lcur[b] = (c > 0) ? atomicAdd(&bincur[b], c) : 0;
    }
    __syncthreads();
    for (int e = base + t; e < end; e += 256) {
        int d = dst[e];
        int bin = d >> BINSHIFT;
        int r = atomicAdd(&lcur[bin], 1);
        ebuf[r] = src[e] | ((d & (BINSIZE - 1)) << 24);
    }
}

// Pass C: one block per bin. LDS degree count -> LDS scan -> rowptr/dinv
// writes -> col scatter with LDS cursors. No global per-node atomics.
__global__ __launch_bounds__(256) void build_csr_k(
    const int* __restrict__ ebuf, const int* __restrict__ binptr,
    int* __restrict__ rowptr, float* __restrict__ dinv,
    int* __restrict__ col, int N, int E, int nbin) {
    __shared__ int lcnt[BINSIZE];
    __shared__ int lscan[BINSIZE];
    __shared__ int lcur[BINSIZE];
    int b = blockIdx.x;
    int t = threadIdx.x;
    int n0 = b << BINSHIFT;
    int e0 = binptr[b];
    int e1 = binptr[b + 1];

    lcnt[t] = 0;
    __syncthreads();
    for (int i = e0 + t; i < e1; i += 256)
        atomicAdd(&lcnt[((unsigned)ebuf[i]) >> 24], 1);
    __syncthreads();

    // inclusive scan of lcnt -> lscan
    int v = lcnt[t];
    lscan[t] = v;
    __syncthreads();
    for (int off = 1; off < 256; off <<= 1) {
        int tv = (t >= off) ? lscan[t - off] : 0;
        __syncthreads();
        lscan[t] += tv;
        __syncthreads();
    }
    int excl = e0 + lscan[t] - v;
    lcur[t] = excl;
    if (n0 + t < N) {
        rowptr[n0 + t] = excl;
        dinv[n0 + t] = 1.0f / sqrtf((float)(v + 1));
    }
    if (b == nbin - 1 && t == 0) rowptr[N] = E;
    __syncthreads();

    for (int i = e0 + t; i < e1; i += 256) {
        int w = ebuf[i];
        int dl = ((unsigned)w) >> 24;
        int p = atomicAdd(&lcur[dl], 1);
        col[p] = w & 0xFFFFFF;
    }
}

// ---------------- GEMM + dinv row-scale:  G = (H @ W) * dinv[row] ----------------
// Block: 256 threads -> 64 rows x 64 cols, each thread 4x4 outputs.
// Manual 1-deep pipeline on the A loads; unroll 1 keeps VGPR < 128.
template <int K>
__global__ __launch_bounds__(256, 4) void gemm_scale_k(
    const float* __restrict__ H, const float* __restrict__ W,
    const float* __restrict__ dinv, float* __restrict__ G, int N) {
    __shared__ float Ws[K * EMB];
    int t = threadIdx.x;
    for (int i = t * 4; i < K * EMB; i += 1024) {
        *(float4*)(Ws + i) = *(const float4*)(W + i);
    }
    __syncthreads();

    int tc = t & 15;   // col group -> 4 cols
    int tr = t >> 4;   // row group -> 4 rows
    int j0 = tc * 4;
    int r0 = blockIdx.x * 64 + tr * 4;
    if (r0 >= N) return;

    const float* hp[4];
#pragma unroll
    for (int i = 0; i < 4; i++) {
        int r = (r0 + i < N) ? (r0 + i) : (N - 1);
        hp[i] = H + (size_t)r * K;
    }

    float acc[4][4] = {{0.f}};
    float4 a[4], an[4];
#pragma unroll
    for (int i = 0; i < 4; i++) a[i] = *(const float4*)(hp[i]);

#pragma unroll 1
    for (int k = 0; k < K; k += 4) {
        if (k + 4 < K) {
#pragma unroll
            for (int i = 0; i < 4; i++) an[i] = *(const float4*)(hp[i] + k + 4);
        }
#pragma unroll
        for (int kk = 0; kk < 4; kk++) {
            float4 wv = *(const float4*)(Ws + (k + kk) * EMB + j0);
#pragma unroll
            for (int i = 0; i < 4; i++) {
                float av = (kk == 0) ? a[i].x : (kk == 1) ? a[i].y : (kk == 2) ? a[i].z : a[i].w;
                acc[i][0] = fmaf(av, wv.x, acc[i][0]);
                acc[i][1] = fmaf(av, wv.y, acc[i][1]);
                acc[i][2] = fmaf(av, wv.z, acc[i][2]);
                acc[i][3] = fmaf(av, wv.w, acc[i][3]);
            }
        }
#pragma unroll
        for (int i = 0; i < 4; i++) a[i] = an[i];
    }

#pragma unroll
    for (int i = 0; i < 4; i++) {
        if (r0 + i < N) {
            float s = dinv[r0 + i];
            float4 o = make_float4(acc[i][0] * s, acc[i][1] * s, acc[i][2] * s, acc[i][3] * s);
            *(float4*)(G + (size_t)(r0 + i) * EMB + j0) = o;
        }
    }
}

// ---------------- Aggregation: one wave per node, one lane per feature ----------------

__device__ __forceinline__ float agg_node(const float* __restrict__ G,
                                          const int* __restrict__ col,
                                          int s, int e, int node, int lane) {
    float a0 = G[(size_t)node * EMB + lane];  // self loop
    float a1 = 0.f, a2 = 0.f, a3 = 0.f;
    int i = s;
    for (; i + 4 <= e; i += 4) {
        int s0 = __builtin_amdgcn_readfirstlane(col[i]);
        int s1 = __builtin_amdgcn_readfirstlane(col[i + 1]);
        int s2 = __builtin_amdgcn_readfirstlane(col[i + 2]);
        int s3 = __builtin_amdgcn_readfirstlane(col[i + 3]);
        float g0 = G[(size_t)s0 * EMB + lane];
        float g1 = G[(size_t)s1 * EMB + lane];
        float g2 = G[(size_t)s2 * EMB + lane];
        float g3 = G[(size_t)s3 * EMB + lane];
        a0 += g0; a1 += g1; a2 += g2; a3 += g3;
    }
    for (; i < e; i++) {
        int s0 = __builtin_amdgcn_readfirstlane(col[i]);
        a0 += G[(size_t)s0 * EMB + lane];
    }
    return (a0 + a1) + (a2 + a3);
}

__global__ __launch_bounds__(256) void agg_k(
    const float* __restrict__ G, const float* __restrict__ dinv,
    const int* __restrict__ rowptr, const int* __restrict__ col,
    const float* __restrict__ bias, float* __restrict__ Hout, int N) {
    int gw = (blockIdx.x * 256 + threadIdx.x) >> 6;
    int lane = threadIdx.x & 63;
    if (gw >= N) return;
    int s = rowptr[gw], e = rowptr[gw + 1];
    float acc = agg_node(G, col, s, e, gw, lane);
    Hout[(size_t)gw * EMB + lane] = acc * dinv[gw] + bias[lane];
}

// Final layer: also project y @ Wout + bout into Out.
__global__ __launch_bounds__(256) void agg_final_k(
    const float* __restrict__ G, const float* __restrict__ dinv,
    const int* __restrict__ rowptr, const int* __restrict__ col,
    const float* __restrict__ bias, const float* __restrict__ Wout,
    const float* __restrict__ bout, float* __restrict__ Y,
    float* __restrict__ Out, int N) {
    int gw = (blockIdx.x * 256 + threadIdx.x) >> 6;
    int lane = threadIdx.x & 63;
    if (gw >= N) return;
    int s = rowptr[gw], e = rowptr[gw + 1];
    float acc = agg_node(G, col, s, e, gw, lane);
    float val = acc * dinv[gw] + bias[lane];
    Y[(size_t)gw * EMB + lane] = val;
    float p = val * Wout[lane];
#pragma unroll
    for (int off = 32; off > 0; off >>= 1) p += __shfl_down(p, off, 64);
    if (lane == 0) Out[gw] = p + bout[0];
}

// ---------------- launch ----------------

extern "C" void kernel_launch(void* const* d_in, const int* in_sizes, int n_in,
                              void* d_out, int out_size, void* d_ws, size_t ws_size,
                              hipStream_t stream) {
    const float* x    = (const float*)d_in[0];
    const int*   ei   = (const int*)d_in[1];
    const float* W0   = (const float*)d_in[3];
    const float* b0   = (const float*)d_in[4];
    const float* W1   = (const float*)d_in[5];
    const float* b1   = (const float*)d_in[6];
    const float* W2   = (const float*)d_in[7];
    const float* b2   = (const float*)d_in[8];
    const float* W3   = (const float*)d_in[9];
    const float* b3   = (const float*)d_in[10];
    const float* Wout = (const float*)d_in[11];
    const float* bout = (const float*)d_in[12];

    const int N = in_sizes[0] / FEAT;      // 100000
    const int E = in_sizes[1] / 2;         // 3200000
    const int* srcp = ei;                  // edge_index[0]
    const int* dstp = ei + E;              // edge_index[1]
    const int nbin = (N + BINSIZE - 1) / BINSIZE;   // 391

    // workspace layout (regions padded to 64 elems for float4 alignment)
    const int NP = ((N + 64) + 63) / 64 * 64;   // holds N+1
    float* dinv  = (float*)d_ws;
    int* rowptr  = (int*)(dinv + NP);
    int* bincnt  = rowptr + NP;
    int* binptr  = bincnt + 1024;
    int* bincur  = binptr + 1024;
    int* col     = bincur + 1024;
    float* bufA  = (float*)(col + ((E + 63) / 64) * 64);
    int* ebuf    = (int*)bufA;            // aliased: ebuf dead before first gemm

    float* Out = (float*)d_out;
    float* Y   = Out + N;                 // reuse y-region of d_out as ping-pong buffer

    const int gemm_blocks = (N + 63) / 64;
    const int agg_blocks  = (N + 3) / 4;
    const int nchunk = (E + CHUNK - 1) / CHUNK;

    // --- CSR build ---
    zero_k<<<1, 1024, 0, stream>>>(bincnt, 1024);
    bin_count_k<<<nchunk, 256, 0, stream>>>(dstp, bincnt, E);
    binscan_k<<<1, 512, 0, stream>>>(bincnt, binptr, bincur, nbin, E);
    bin_edges_k<<<nchunk, 256, 0, stream>>>(srcp, dstp, bincur, ebuf, E);
    build_csr_k<<<nbin, 256, 0, stream>>>(ebuf, binptr, rowptr, dinv, col, N, E, nbin);

    // --- layer 0 (K=128) ---
    gemm_scale_k<FEAT><<<gemm_blocks, 256, 0, stream>>>(x, W0, dinv, bufA, N);
    agg_k<<<agg_blocks, 256, 0, stream>>>(bufA, dinv, rowptr, col, b0, Y, N);
    // --- layer 1 ---
    gemm_scale_k<EMB><<<gemm_blocks, 256, 0, stream>>>(Y, W1, dinv, bufA, N);
    agg_k<<<agg_blocks, 256, 0, stream>>>(bufA, dinv, rowptr, col, b1, Y, N);
    // --- layer 2 ---
    gemm_scale_k<EMB><<<gemm_blocks, 256, 0, stream>>>(Y, W2, dinv, bufA, N);
    agg_k<<<agg_blocks, 256, 0, stream>>>(bufA, dinv, rowptr, col, b2, Y, N);
    // --- layer 3 + output projection ---
    gemm_scale_k<EMB><<<gemm_blocks, 256, 0, stream>>>(Y, W3, dinv, bufA, N);
    agg_final_k<<<agg_blocks, 256, 0, stream>>>(bufA, dinv, rowptr, col, b3, Wout, bout,
                                                Y, Out, N);
}